// Round 25
// baseline (159.260 us; speedup 1.0000x reference)
//
#include <hip/hip_runtime.h>

#define BB 128
#define TT 224
#define LL 224

typedef float v2f __attribute__((ext_vector_type(2)));

__device__ __forceinline__ float rcpf(float x){ return __builtin_amdgcn_rcpf(x); }

#if __has_builtin(__builtin_amdgcn_exp2f)
#define EXP2(x) __builtin_amdgcn_exp2f(x)
#else
#define EXP2(x) __expf((x)*0.6931471805599453f)
#endif

// DPP row rotate-right by N: dst[k] = src[(k-N)&15] within each 16-lane row
template<int N>
__device__ __forceinline__ float rorN(float x){
  int xi = __builtin_bit_cast(int, x);
  xi = __builtin_amdgcn_update_dpp(xi, xi, 0x120 + N, 0xf, 0xf, false);
  return __builtin_bit_cast(float, xi);
}

// v_permlane32_swap_b32: with a==b==x -> a'=low-half bcast, b'=high-half bcast
__device__ __forceinline__ void swap32(float& a, float& b){
  asm volatile("s_nop 1\n\tv_permlane32_swap_b32 %0, %1\n\ts_nop 1"
               : "+v"(a), "+v"(b));
}

// ---------------- shared LSTM step macro ----------------------------------
#define LSTM_STEP(P, SS) { \
  float x1=rorN<1>(hv), x2=rorN<2>(hv), x3=rorN<3>(hv), x4=rorN<4>(hv), \
        x5=rorN<5>(hv), x6=rorN<6>(hv), x7=rorN<7>(hv), x8=rorN<8>(hv), \
        x9=rorN<9>(hv), x10=rorN<10>(hv), x11=rorN<11>(hv), x12=rorN<12>(hv), \
        x13=rorN<13>(hv), x14=rorN<14>(hv), x15=rorN<15>(hv); \
  v2f a0 = (P); \
  a0 += w[0]*(v2f){hv,hv};   a0 += w[1]*(v2f){x1,x1};   a0 += w[2]*(v2f){x2,x2};   a0 += w[3]*(v2f){x3,x3}; \
  v2f a1 = w[4]*(v2f){x4,x4};   a1 += w[5]*(v2f){x5,x5};   a1 += w[6]*(v2f){x6,x6};   a1 += w[7]*(v2f){x7,x7}; \
  v2f a2 = w[8]*(v2f){x8,x8};   a2 += w[9]*(v2f){x9,x9};   a2 += w[10]*(v2f){x10,x10}; a2 += w[11]*(v2f){x11,x11}; \
  v2f a3 = w[12]*(v2f){x12,x12}; a3 += w[13]*(v2f){x13,x13}; a3 += w[14]*(v2f){x14,x14}; a3 += w[15]*(v2f){x15,x15}; \
  v2f gg = (a0+a1)+(a2+a3); \
  v2f m  = gg*kmul; \
  v2f e  = { EXP2(m.x), EXP2(m.y) }; \
  e += (v2f){1.f,1.f}; \
  v2f d  = { rcpf(e.x), rcpf(e.y) }; \
  v2f res = ca*d + cb; \
  float p0 = res.x, p1 = res.x; swap32(p0, p1); \
  float q0 = res.y, q1 = res.y; swap32(q0, q1); \
  cst = fmaf(q0, cst, p0*p1); \
  float et = EXP2(cst*2.885390082f); \
  float dt = rcpf(et+1.f); \
  hv = q1*fmaf(-2.f, dt, 1.f); \
  hbuf[SS] = hv; }

#define FLUSH8 { \
  if (doSt){ \
    _Pragma("unroll") \
    for (int q=0;q<8;q++) outP[q*ostep] = hbuf[q]; \
  } \
  outP += 8*ostep; }

// lstm weight/constant prep (shared by both fused kernels)
#define LSTM_PREP(WHH) \
  v2f w[16]; \
  _Pragma("unroll") \
  for (int rr=0; rr<16; rr++){ \
    int j = (u - rr) & 15; \
    bool vld = (j < 12) && (u < 12); \
    int uw = (u < 12) ? u : 0; \
    int jw = (j < 12) ? j : 0; \
    float wa = (WHH)[((rbit?24:0)  + uw)*12 + jw]; \
    float wb = (WHH)[((rbit?36:12) + uw)*12 + jw]; \
    w[rr] = (v2f){ vld ? wa : 0.f, vld ? wb : 0.f }; \
  } \
  const v2f kmul = rbit ? (v2f){2.885390082f, -1.442695041f} \
                        : (v2f){-1.442695041f, -1.442695041f}; \
  const v2f ca   = rbit ? (v2f){-2.f, 1.f} : (v2f){1.f, 1.f}; \
  const v2f cb   = rbit ? (v2f){ 1.f, 0.f} : (v2f){0.f, 0.f};

// consumer main loop over LDS lpre with producer flags pv[1],pv[2]
#define LSTM_CONSUME_LDS(LPRE, OUTBUF) { \
  float* preR = (LPRE) + bh*(224*48) + keff*4 + rbit*2; \
  const int sstep = dir ? -48 : 48; \
  int scb = dir ? 223*48 : 0; \
  volatile int* pv = prog; \
  while (pv[1] < 2 || pv[2] < 2) __builtin_amdgcn_s_sleep(2); \
  asm volatile("" ::: "memory"); \
  v2f pcur[8], pnext[8]; \
  _Pragma("unroll") \
  for (int i=0;i<8;i++) pcur[i]  = *(const v2f*)(preR + scb +  i   *sstep); \
  _Pragma("unroll") \
  for (int i=0;i<8;i++) pnext[i] = *(const v2f*)(preR + scb + (i+8)*sstep); \
  int lb = scb + 16*sstep; \
  float hv = 0.f, cst = 0.f; \
  float hbuf[8]; \
  const int ostep = dir ? -24 : 24; \
  float* outP = (OUTBUF) + (size_t)br*(BB*TT*24) + (size_t)b*TT*24 + dir*12 + u \
              + (size_t)(dir ? 223 : 0)*24; \
  const bool doSt = (rbit==0) && (u < 12); \
  for (int c=0;c<14;c++){ \
    LSTM_STEP(pcur[0],0) LSTM_STEP(pcur[1],1) LSTM_STEP(pcur[2],2) LSTM_STEP(pcur[3],3) \
    LSTM_STEP(pcur[4],4) LSTM_STEP(pcur[5],5) LSTM_STEP(pcur[6],6) LSTM_STEP(pcur[7],7) \
    FLUSH8 \
    if (c < 13){ \
      int nd_ = 2*c+3; \
      while (pv[1] < nd_ || pv[2] < nd_) __builtin_amdgcn_s_sleep(2); \
      asm volatile("" ::: "memory"); \
      _Pragma("unroll") \
      for (int i=0;i<8;i++) pcur[i] = *(const v2f*)(preR + lb + i*sstep); \
      lb += 8*sstep; \
    } \
    LSTM_STEP(pnext[0],0) LSTM_STEP(pnext[1],1) LSTM_STEP(pnext[2],2) LSTM_STEP(pnext[3],3) \
    LSTM_STEP(pnext[4],4) LSTM_STEP(pnext[5],5) LSTM_STEP(pnext[6],6) LSTM_STEP(pnext[7],7) \
    FLUSH8 \
    if (c < 13){ \
      int nd_ = 2*c+4; \
      while (pv[1] < nd_ || pv[2] < nd_) __builtin_amdgcn_s_sleep(2); \
      asm volatile("" ::: "memory"); \
      _Pragma("unroll") \
      for (int i=0;i<8;i++) pnext[i] = *(const v2f*)(preR + lb + i*sstep); \
      lb += 8*sstep; \
    } \
  } }

// ---- K0: fcA — wpartA with inline 4-wave Wt tile + BCpart ---------------
__global__ __launch_bounds__(256) void fcA_kernel(
    const float* __restrict__ fcw1, const float* __restrict__ fcw2,
    const float* __restrict__ fcw3, const float* __restrict__ fcb1,
    float* __restrict__ wpart, float* __restrict__ BCpart)
{
  __shared__ float sb[2880];
  int gb  = blockIdx.x;           // 0..335
  int tid = threadIdx.x;
  int s     = gb / 21;
  int jtile = gb % 21;
  float* wtp = sb;                // 4 x 576
  float* wt  = sb + 2304;         // 576
  {
    int wave = tid >> 6, lane = tid & 63;
    float acc[9];
    #pragma unroll
    for (int q=0;q<9;q++) acc[q]=0.f;
    const float* f2 = fcw2 + s*64 + lane;
    int p0 = wave*48;
    #pragma unroll 4
    for (int pp=0; pp<48; pp++){
      int p = p0 + pp;
      float v = f2[(size_t)p*1024];
      #pragma unroll
      for (int q=0;q<9;q++) acc[q] += fcw3[q*192+p]*v;
    }
    #pragma unroll
    for (int q=0;q<9;q++) wtp[wave*576 + q*64 + lane] = acc[q];
  }
  __syncthreads();
  for (int i = tid; i < 576; i += 256)
    wt[i] = wtp[i] + wtp[576+i] + wtp[1152+i] + wtp[1728+i];
  __syncthreads();

  int j = jtile*256 + tid;
  int nbase = s*64;
  float acc[9];
  #pragma unroll
  for (int o=0;o<9;o++) acc[o]=0.f;
  #pragma unroll 4
  for (int n4=0;n4<16;n4++){
    int nb = nbase + n4*4;
    float4 v4;
    v4.x = fcw1[(size_t)(nb  )*5376 + j];
    v4.y = fcw1[(size_t)(nb+1)*5376 + j];
    v4.z = fcw1[(size_t)(nb+2)*5376 + j];
    v4.w = fcw1[(size_t)(nb+3)*5376 + j];
    #pragma unroll
    for (int o=0;o<9;o++){
      float4 w4 = *(const float4*)&wt[o*64 + n4*4];
      acc[o] += v4.x*w4.x + v4.y*w4.y + v4.z*w4.z + v4.w*w4.w;
    }
  }
  #pragma unroll
  for (int o=0;o<9;o++) wpart[((size_t)s*9+o)*5376 + j] = acc[o];
  if (jtile == 0 && tid < 9){
    float bcp = 0.f;
    for (int n=0;n<64;n++) bcp += wt[tid*64+n]*fcb1[nbase+n];
    BCpart[s*9+tid] = bcp;
  }
}

// ---- K1: layer-1 FUSED: wave0 = lstm consumer; wave1 = conv y-producer; --
// waves2-3 = pregate gate-producers. Chain y->gate->consumer via LDS flags.
__global__ __launch_bounds__(256) __attribute__((amdgpu_waves_per_eu(1,1)))
void lstm1_fused_kernel(const float* __restrict__ x,
    const float* __restrict__ whhA, const float* __restrict__ whhB,
    const float* __restrict__ wihA, const float* __restrict__ biasA,
    const float* __restrict__ wihB, const float* __restrict__ biasB,
    const float* __restrict__ c1w1, const float* __restrict__ c1b1,
    const float* __restrict__ c1w2, const float* __restrict__ c1b2,
    const float* __restrict__ c2w1, const float* __restrict__ c2b1,
    const float* __restrict__ c2w2, const float* __restrict__ c2b2,
    float* __restrict__ out)
{
  __shared__ float lpre[2*224*48];     // 86016 B
  __shared__ float ybuf[2*224*28];     // 50176 B
  __shared__ float c1s[16*57];         // 3648 B
  __shared__ int prog[8];              // [0]=y, [1]=gate wave2, [2]=gate wave3
  int tid  = threadIdx.x;
  int blk  = blockIdx.x;
  int r    = blk >> 6;
  int br   = r >> 1, dir = r & 1;
  int b0   = (blk & 63)*2;

  if (tid < 8) ((volatile int*)prog)[tid] = 0;
  __syncthreads();

  if (tid >= 64 && tid < 128){
    // ---------------- y-producer (conv1 -> pool -> conv2) ----------------
    int p    = tid - 64;          // 0..63
    int rowq = p >> 2;            // 0..15 : bb*8 + ti
    int q    = p & 3;             // quarter of row
    int bb   = rowq >> 3;
    int ti   = rowq & 7;
    int cjs  = q*14;
    const float* w1 = br ? c2w1 : c1w1;
    const float* w2 = br ? c2w2 : c1w2;
    float b1  = br ? c2b1[0] : c1b1[0];
    float b2v = br ? c2b2[0] : c1b2[0];
    float w1r[8];
    #pragma unroll
    for (int kk=0;kk<8;kk++) w1r[kk]=w1[kk];
    float w2r[3];
    #pragma unroll
    for (int kk=0;kk<3;kk++) w2r[kk]=w2[kk];
    const float* xb = x + ((size_t)(br*128 + b0 + bb))*50176;
    volatile int* pv = prog;
    int a0 = 4*cjs - 4;

    for (int g=0; g<28; ++g){
      int step = g*8 + ti;
      int t = dir ? 223-step : step;
      const float* xrow = xb + (size_t)t*224;
      float xr[64];
      #pragma unroll
      for (int qq=0; qq<16; qq++){
        int idx = a0 + 4*qq;
        if (idx >= 0 && idx <= 220){
          float4 v = *(const float4*)(xrow + idx);
          xr[4*qq]=v.x; xr[4*qq+1]=v.y; xr[4*qq+2]=v.z; xr[4*qq+3]=v.w;
        } else {
          #pragma unroll
          for (int e=0;e<4;e++){
            int ii = idx+e;
            xr[4*qq+e] = (ii>=0 && ii<224) ? xrow[ii] : 0.f;
          }
        }
      }
      #pragma unroll
      for (int e=0;e<14;e++){
        float s = b1;
        #pragma unroll
        for (int kk=0;kk<8;kk++) s += xr[4*e+2+kk]*w1r[kk];
        c1s[rowq*57 + cjs + e] = fmaxf(s, 0.f);
      }
      asm volatile("s_waitcnt lgkmcnt(0)" ::: "memory");
      const float* cr = &c1s[rowq*57];
      #pragma unroll
      for (int jj=0;jj<7;jj++){
        int j = q*7 + jj;
        float o = b2v;
        #pragma unroll
        for (int pi=0;pi<3;pi++){
          int pp = j - 1 + pi;
          float pool = 0.f;
          if (pp>=0 && pp<28){
            int i0 = 2*pp - 1;
            float m = -1e30f;
            #pragma unroll
            for (int q2=0;q2<4;q2++){
              int ii = i0+q2;
              if (ii>=0 && ii<56) m = fmaxf(m, cr[ii]);
            }
            pool = fmaxf(m, 0.f);
          }
          o += pool * w2r[pi];
        }
        ybuf[(bb*224 + t)*28 + j] = fmaxf(o, 0.f);
      }
      asm volatile("s_waitcnt lgkmcnt(0)" ::: "memory");
      if (p == 0) pv[0] = g+1;
    }
    return;
  }

  if (tid >= 128){
    // ---------------- gate-producers (pregate from ybuf) -----------------
    int p2 = tid - 128;           // 0..127
    if (p2 >= 96) return;
    int fidx = (tid >> 6) - 1;    // 1 for wave2, 2 for wave3
    int bb   = p2 / 48;
    int gate = p2 % 48;
    const float* wih2 = (br ? wihB : wihA) + (dir*48 + gate)*28;
    float4 wq[7];
    #pragma unroll
    for (int q=0;q<7;q++) wq[q] = ((const float4*)wih2)[q];
    float bias = (br ? biasB : biasA)[dir*48 + gate];
    int unit = gate % 12, gg = gate / 12;
    float* lrow = lpre + bb*(224*48) + unit*4 + gg;
    volatile int* pv = prog;

    for (int g=0; g<28; ++g){
      while (pv[0] < g+1) __builtin_amdgcn_s_sleep(2);
      asm volatile("" ::: "memory");
      #pragma unroll
      for (int si=0; si<8; si++){
        int t = dir ? 223-(g*8+si) : (g*8+si);
        const float4* yr = (const float4*)&ybuf[(bb*224 + t)*28];
        float a = bias;
        #pragma unroll
        for (int q=0;q<7;q++){
          float4 yq = yr[q];
          a += yq.x*wq[q].x + yq.y*wq[q].y + yq.z*wq[q].z + yq.w*wq[q].w;
        }
        lrow[t*48] = a;
      }
      asm volatile("s_waitcnt lgkmcnt(0)" ::: "memory");
      if ((p2 & 63) == 0) pv[fidx] = g+1;
    }
    return;
  }

  // ---------------- consumer (lstm chain) ----------------
  int lane = tid;
  int u    = lane & 15;
  int bh   = (lane >> 4) & 1;
  int rbit = lane >> 5;
  int keff = (u < 12) ? u : 11;
  int b    = b0 + bh;
  const float* whh = (br ? whhB : whhA) + dir*48*12;
  LSTM_PREP(whh)
  LSTM_CONSUME_LDS(lpre, out)
}

// ---- K3b: layer-2 FUSED (R24-proven): wave0 consumer, waves1-3 pregate ---
__global__ __launch_bounds__(256) __attribute__((amdgpu_waves_per_eu(1,1)))
void lstm2_fused_kernel(const float* __restrict__ ol0,
    const float* __restrict__ whhA, const float* __restrict__ whhB,
    const float* __restrict__ wihA, const float* __restrict__ biasA,
    const float* __restrict__ wihB, const float* __restrict__ biasB,
    float* __restrict__ out)
{
  __shared__ float lpre[2*224*48];     // 86016 B
  __shared__ int prog[8];              // use [1],[2] for waves 1-2; [3] folded
  int tid  = threadIdx.x;
  int blk  = blockIdx.x;
  int r    = blk >> 6;
  int br   = r >> 1, dir = r & 1;
  int b0   = (blk & 63)*2;

  if (tid < 8) ((volatile int*)prog)[tid] = 0;
  __syncthreads();

  if (tid >= 64){
    int p    = tid - 64;          // 0..191
    int wv   = p >> 6;            // 0..2
    int e    = p % 96;
    int th   = p / 96;            // 0/1 half
    int bb   = e / 48;
    int gate = e % 48;
    const float* wih2 = (br ? wihB : wihA) + (dir*48 + gate)*24;
    float4 wq[6];
    #pragma unroll
    for (int q=0;q<6;q++) wq[q] = ((const float4*)wih2)[q];
    float bias = (br ? biasB : biasA)[dir*48 + gate];
    int unit = gate % 12, gg = gate / 12;
    const float* olrow = ol0 + (size_t)br*(BB*TT*24) + (size_t)(b0+bb)*TT*24;
    float* lrow = lpre + bb*(224*48) + unit*4 + gg;
    volatile int* pv = prog;

    for (int g=0; g<28; g++){
      #pragma unroll
      for (int si=0; si<4; si++){
        int step = g*8 + th*4 + si;
        int t = dir ? 223 - step : step;
        const float4* xr = (const float4*)(olrow + t*24);
        float a = bias;
        #pragma unroll
        for (int q=0;q<6;q++){
          float4 xq = xr[q];
          a += xq.x*wq[q].x + xq.y*wq[q].y + xq.z*wq[q].z + xq.w*wq[q].w;
        }
        lrow[t*48] = a;
      }
      asm volatile("s_waitcnt lgkmcnt(0) vmcnt(0)" ::: "memory");
      if ((p & 63) == 0) pv[wv] = g+1;
    }
    return;
  }

  int lane = tid;
  int u    = lane & 15;
  int bh   = (lane >> 4) & 1;
  int rbit = lane >> 5;
  int keff = (u < 12) ? u : 11;
  int b    = b0 + bh;
  const float* whh = (br ? whhB : whhA) + dir*48*12;
  LSTM_PREP(whh)
  // consumer waits on pv[0],pv[1],pv[2] here: reuse macro via pv[1],pv[2]
  // but R24 waited on all three; emulate by also checking pv[0] via pv[1]
  {
    float* preR = lpre + bh*(224*48) + keff*4 + rbit*2;
    const int sstep = dir ? -48 : 48;
    int scb = dir ? 223*48 : 0;
    volatile int* pv = prog;
#define WAITG3(NEED) { int nd_ = (NEED); \
  while (pv[0] < nd_ || pv[1] < nd_ || pv[2] < nd_) __builtin_amdgcn_s_sleep(2); \
  asm volatile("" ::: "memory"); }
    WAITG3(2)
    v2f pcur[8], pnext[8];
    #pragma unroll
    for (int i=0;i<8;i++) pcur[i]  = *(const v2f*)(preR + scb +  i   *sstep);
    #pragma unroll
    for (int i=0;i<8;i++) pnext[i] = *(const v2f*)(preR + scb + (i+8)*sstep);
    int lb = scb + 16*sstep;
    float hv = 0.f, cst = 0.f;
    float hbuf[8];
    const int ostep = dir ? -24 : 24;
    float* outP = out + (size_t)br*(BB*TT*24) + (size_t)b*TT*24 + dir*12 + u
                + (size_t)(dir ? 223 : 0)*24;
    const bool doSt = (rbit==0) && (u < 12);
    for (int c=0;c<14;c++){
      LSTM_STEP(pcur[0],0) LSTM_STEP(pcur[1],1) LSTM_STEP(pcur[2],2) LSTM_STEP(pcur[3],3)
      LSTM_STEP(pcur[4],4) LSTM_STEP(pcur[5],5) LSTM_STEP(pcur[6],6) LSTM_STEP(pcur[7],7)
      FLUSH8
      if (c < 13){
        WAITG3(2*c+3)
        #pragma unroll
        for (int i=0;i<8;i++) pcur[i] = *(const v2f*)(preR + lb + i*sstep);
        lb += 8*sstep;
      }
      LSTM_STEP(pnext[0],0) LSTM_STEP(pnext[1],1) LSTM_STEP(pnext[2],2) LSTM_STEP(pnext[3],3)
      LSTM_STEP(pnext[4],4) LSTM_STEP(pnext[5],5) LSTM_STEP(pnext[6],6) LSTM_STEP(pnext[7],7)
      FLUSH8
      if (c < 13){
        WAITG3(2*c+4)
        #pragma unroll
        for (int i=0;i<8;i++) pnext[i] = *(const v2f*)(preR + lb + i*sstep);
        lb += 8*sstep;
      }
    }
#undef WAITG3
  }
}

// -------- K4: wpartB (Wc reduce) + BC finalize ----------------------------
__global__ __launch_bounds__(256) void wpartB_kernel(
    const float* __restrict__ wpart, float* __restrict__ Wc,
    const float* __restrict__ fcw3, const float* __restrict__ fcb2,
    const float* __restrict__ fcb3, const float* __restrict__ BCpart,
    float* __restrict__ BC)
{
  int gb  = blockIdx.x;
  int tid = threadIdx.x;
  if (gb < 189){
    int idx = gb*256 + tid;   // 189*256 = 48384
    float a = 0.f;
    #pragma unroll
    for (int s=0;s<16;s++) a += wpart[(size_t)s*48384 + idx];
    Wc[idx] = a;
  } else if (tid < 9){
    float acc = fcb3[tid];
    const float* f3 = fcw3 + tid*192;
    for (int p=0;p<192;p++) acc += f3[p]*fcb2[p];
    #pragma unroll
    for (int s=0;s<16;s++) acc += BCpart[s*9+tid];
    BC[tid] = acc;
  }
}

// ---------------- K6c: out[m][o] = (w1*o1+w2*o2) . Wc[o] + BC[o] ----------
__global__ void final_kernel(const float* __restrict__ o1, const float* __restrict__ o2,
    const float* __restrict__ Wc, const float* __restrict__ BC,
    const float* __restrict__ w1p, const float* __restrict__ w2p,
    float* __restrict__ out)
{
  int wid  = blockIdx.x*4 + (threadIdx.x>>6);
  int lane = threadIdx.x & 63;
  if (wid >= 128*9) return;
  int m = wid / 9, o = wid - m*9;
  float w1 = w1p[0], w2 = w2p[0];
  const float* r1 = o1 + (size_t)m*5376;
  const float* r2 = o2 + (size_t)m*5376;
  const float* wc = Wc + (size_t)o*5376;
  float acc = 0.f;
  for (int i=lane;i<5376;i+=64){
    acc += (w1*r1[i] + w2*r2[i]) * wc[i];
  }
  #pragma unroll
  for (int off=32;off;off>>=1) acc += __shfl_down(acc, off);
  if (lane==0) out[m*9+o] = acc + BC[o];
}

extern "C" void kernel_launch(void* const* d_in, const int* in_sizes, int n_in,
                              void* d_out, int out_size, void* d_ws, size_t ws_size,
                              hipStream_t stream) {
  (void)in_sizes; (void)n_in; (void)out_size; (void)ws_size;
  const float* x    = (const float*)d_in[0];
  const float* c1w1 = (const float*)d_in[1];
  const float* c1b1 = (const float*)d_in[2];
  const float* c1w2 = (const float*)d_in[3];
  const float* c1b2 = (const float*)d_in[4];
  const float* c2w1 = (const float*)d_in[5];
  const float* c2b1 = (const float*)d_in[6];
  const float* c2w2 = (const float*)d_in[7];
  const float* c2b2 = (const float*)d_in[8];
  const float* l10Wih = (const float*)d_in[9];
  const float* l10Whh = (const float*)d_in[10];
  const float* l10b   = (const float*)d_in[11];
  const float* l11Wih = (const float*)d_in[12];
  const float* l11Whh = (const float*)d_in[13];
  const float* l11b   = (const float*)d_in[14];
  const float* l20Wih = (const float*)d_in[15];
  const float* l20Whh = (const float*)d_in[16];
  const float* l20b   = (const float*)d_in[17];
  const float* l21Wih = (const float*)d_in[18];
  const float* l21Whh = (const float*)d_in[19];
  const float* l21b   = (const float*)d_in[20];
  const float* fcw1 = (const float*)d_in[21];
  const float* fcb1 = (const float*)d_in[22];
  const float* fcw2 = (const float*)d_in[23];
  const float* fcb2 = (const float*)d_in[24];
  const float* fcw3 = (const float*)d_in[25];
  const float* fcb3 = (const float*)d_in[26];
  const float* w1   = (const float*)d_in[27];
  const float* w2   = (const float*)d_in[28];
  float* out = (float*)d_out;

  float* ws  = (float*)d_ws;
  float* wpart = ws;                      // 774144
  float* ol0  = ws + 2*802816 + 4*1376256;   // keep prior offsets
  float* ol1  = ol0 + 2*688128;
  float* Wc   = ol1 + 2*688128;
  float* BC   = Wc  + 48384;
  float* BCpart = BC + 9;

  fcA_kernel<<<336,256,0,stream>>>(fcw1, fcw2, fcw3, fcb1, wpart, BCpart);
  lstm1_fused_kernel<<<256,256,0,stream>>>(x, l10Whh, l20Whh,
      l10Wih, l10b, l20Wih, l20b,
      c1w1,c1b1,c1w2,c1b2, c2w1,c2b1,c2w2,c2b2, ol0);
  wpartB_kernel<<<190,256,0,stream>>>(wpart, Wc, fcw3, fcb2, fcb3, BCpart, BC);
  lstm2_fused_kernel<<<256,256,0,stream>>>(ol0, l11Whh, l21Whh,
      l11Wih, l11b, l21Wih, l21b, ol1);
  final_kernel<<<288,256,0,stream>>>(ol1, ol1+688128, Wc, BC, w1, w2, out);
}

// Round 26
// 152.158 us; speedup vs baseline: 1.0467x; 1.0467x over previous
//
#include <hip/hip_runtime.h>

#define BB 128
#define TT 224
#define LL 224

typedef float v2f __attribute__((ext_vector_type(2)));

__device__ __forceinline__ float rcpf(float x){ return __builtin_amdgcn_rcpf(x); }

#if __has_builtin(__builtin_amdgcn_exp2f)
#define EXP2(x) __builtin_amdgcn_exp2f(x)
#else
#define EXP2(x) __expf((x)*0.6931471805599453f)
#endif

// DPP row rotate-right by N: dst[k] = src[(k-N)&15] within each 16-lane row
template<int N>
__device__ __forceinline__ float rorN(float x){
  int xi = __builtin_bit_cast(int, x);
  xi = __builtin_amdgcn_update_dpp(xi, xi, 0x120 + N, 0xf, 0xf, false);
  return __builtin_bit_cast(float, xi);
}

// v_permlane32_swap_b32: with a==b==x -> a'=low-half bcast, b'=high-half bcast
__device__ __forceinline__ void swap32(float& a, float& b){
  asm volatile("s_nop 1\n\tv_permlane32_swap_b32 %0, %1\n\ts_nop 1"
               : "+v"(a), "+v"(b));
}

// ---------------- shared LSTM step macro ----------------------------------
#define LSTM_STEP(P, SS) { \
  float x1=rorN<1>(hv), x2=rorN<2>(hv), x3=rorN<3>(hv), x4=rorN<4>(hv), \
        x5=rorN<5>(hv), x6=rorN<6>(hv), x7=rorN<7>(hv), x8=rorN<8>(hv), \
        x9=rorN<9>(hv), x10=rorN<10>(hv), x11=rorN<11>(hv), x12=rorN<12>(hv), \
        x13=rorN<13>(hv), x14=rorN<14>(hv), x15=rorN<15>(hv); \
  v2f a0 = (P); \
  a0 += w[0]*(v2f){hv,hv};   a0 += w[1]*(v2f){x1,x1};   a0 += w[2]*(v2f){x2,x2};   a0 += w[3]*(v2f){x3,x3}; \
  v2f a1 = w[4]*(v2f){x4,x4};   a1 += w[5]*(v2f){x5,x5};   a1 += w[6]*(v2f){x6,x6};   a1 += w[7]*(v2f){x7,x7}; \
  v2f a2 = w[8]*(v2f){x8,x8};   a2 += w[9]*(v2f){x9,x9};   a2 += w[10]*(v2f){x10,x10}; a2 += w[11]*(v2f){x11,x11}; \
  v2f a3 = w[12]*(v2f){x12,x12}; a3 += w[13]*(v2f){x13,x13}; a3 += w[14]*(v2f){x14,x14}; a3 += w[15]*(v2f){x15,x15}; \
  v2f gg = (a0+a1)+(a2+a3); \
  v2f m  = gg*kmul; \
  v2f e  = { EXP2(m.x), EXP2(m.y) }; \
  e += (v2f){1.f,1.f}; \
  v2f d  = { rcpf(e.x), rcpf(e.y) }; \
  v2f res = ca*d + cb; \
  float p0 = res.x, p1 = res.x; swap32(p0, p1); \
  float q0 = res.y, q1 = res.y; swap32(q0, q1); \
  cst = fmaf(q0, cst, p0*p1); \
  float et = EXP2(cst*2.885390082f); \
  float dt = rcpf(et+1.f); \
  hv = q1*fmaf(-2.f, dt, 1.f); \
  hbuf[SS] = hv; }

#define FLUSH8 { \
  if (doSt){ \
    _Pragma("unroll") \
    for (int q=0;q<8;q++) outP[q*ostep] = hbuf[q]; \
  } \
  outP += 8*ostep; }

#define LSTM_PREP(WHH) \
  v2f w[16]; \
  _Pragma("unroll") \
  for (int rr=0; rr<16; rr++){ \
    int j = (u - rr) & 15; \
    bool vld = (j < 12) && (u < 12); \
    int uw = (u < 12) ? u : 0; \
    int jw = (j < 12) ? j : 0; \
    float wa = (WHH)[((rbit?24:0)  + uw)*12 + jw]; \
    float wb = (WHH)[((rbit?36:12) + uw)*12 + jw]; \
    w[rr] = (v2f){ vld ? wa : 0.f, vld ? wb : 0.f }; \
  } \
  const v2f kmul = rbit ? (v2f){2.885390082f, -1.442695041f} \
                        : (v2f){-1.442695041f, -1.442695041f}; \
  const v2f ca   = rbit ? (v2f){-2.f, 1.f} : (v2f){1.f, 1.f}; \
  const v2f cb   = rbit ? (v2f){ 1.f, 0.f} : (v2f){0.f, 0.f};

// consumer loop over LDS lpre, waiting on flags pv[0..2]
#define LSTM_CONSUME3(LPRE, OUTBUF) { \
  float* preR = (LPRE) + bh*(224*48) + keff*4 + rbit*2; \
  const int sstep = dir ? -48 : 48; \
  int scb = dir ? 223*48 : 0; \
  volatile int* pv = prog; \
  while (pv[0] < 2 || pv[1] < 2 || pv[2] < 2) __builtin_amdgcn_s_sleep(2); \
  asm volatile("" ::: "memory"); \
  v2f pcur[8], pnext[8]; \
  _Pragma("unroll") \
  for (int i=0;i<8;i++) pcur[i]  = *(const v2f*)(preR + scb +  i   *sstep); \
  _Pragma("unroll") \
  for (int i=0;i<8;i++) pnext[i] = *(const v2f*)(preR + scb + (i+8)*sstep); \
  int lb = scb + 16*sstep; \
  float hv = 0.f, cst = 0.f; \
  float hbuf[8]; \
  const int ostep = dir ? -24 : 24; \
  float* outP = (OUTBUF) + (size_t)br*(BB*TT*24) + (size_t)b*TT*24 + dir*12 + u \
              + (size_t)(dir ? 223 : 0)*24; \
  const bool doSt = (rbit==0) && (u < 12); \
  for (int c=0;c<14;c++){ \
    LSTM_STEP(pcur[0],0) LSTM_STEP(pcur[1],1) LSTM_STEP(pcur[2],2) LSTM_STEP(pcur[3],3) \
    LSTM_STEP(pcur[4],4) LSTM_STEP(pcur[5],5) LSTM_STEP(pcur[6],6) LSTM_STEP(pcur[7],7) \
    FLUSH8 \
    if (c < 13){ \
      int nd_ = 2*c+3; \
      while (pv[0] < nd_ || pv[1] < nd_ || pv[2] < nd_) __builtin_amdgcn_s_sleep(2); \
      asm volatile("" ::: "memory"); \
      _Pragma("unroll") \
      for (int i=0;i<8;i++) pcur[i] = *(const v2f*)(preR + lb + i*sstep); \
      lb += 8*sstep; \
    } \
    LSTM_STEP(pnext[0],0) LSTM_STEP(pnext[1],1) LSTM_STEP(pnext[2],2) LSTM_STEP(pnext[3],3) \
    LSTM_STEP(pnext[4],4) LSTM_STEP(pnext[5],5) LSTM_STEP(pnext[6],6) LSTM_STEP(pnext[7],7) \
    FLUSH8 \
    if (c < 13){ \
      int nd_ = 2*c+4; \
      while (pv[0] < nd_ || pv[1] < nd_ || pv[2] < nd_) __builtin_amdgcn_s_sleep(2); \
      asm volatile("" ::: "memory"); \
      _Pragma("unroll") \
      for (int i=0;i<8;i++) pnext[i] = *(const v2f*)(preR + lb + i*sstep); \
      lb += 8*sstep; \
    } \
  } }

// ---- K0: Wtb[o][n] = fcw3 @ fcw2 (36 blocks, coalesced over n) -----------
__global__ __launch_bounds__(256) void wtb_kernel(
    const float* __restrict__ fcw2, const float* __restrict__ fcw3,
    float* __restrict__ Wtb)
{
  int idx = blockIdx.x*256 + threadIdx.x;   // < 9216
  int o = idx >> 10, n = idx & 1023;
  float acc = 0.f;
  for (int p=0;p<192;p++) acc += fcw3[o*192+p]*fcw2[(size_t)p*1024+n];
  Wtb[idx] = acc;
}

// ---- K1: layer-1 FUSED: wave0 = lstm consumer; wave1 = conv y-producer; --
// waves2-3 = gate-producers. After production, waves 1-3 run wpartA slices
// (Wtb tile -> split-K over fcw1) + BCpart in the consumer's shadow.
__global__ __launch_bounds__(256) __attribute__((amdgpu_waves_per_eu(1,1)))
void lstm1_fused_kernel(const float* __restrict__ x,
    const float* __restrict__ whhA, const float* __restrict__ whhB,
    const float* __restrict__ wihA, const float* __restrict__ biasA,
    const float* __restrict__ wihB, const float* __restrict__ biasB,
    const float* __restrict__ c1w1, const float* __restrict__ c1b1,
    const float* __restrict__ c1w2, const float* __restrict__ c1b2,
    const float* __restrict__ c2w1, const float* __restrict__ c2b1,
    const float* __restrict__ c2w2, const float* __restrict__ c2b2,
    const float* __restrict__ fcw1, const float* __restrict__ fcb1,
    const float* __restrict__ Wtb,
    float* __restrict__ wpart, float* __restrict__ BCpart,
    float* __restrict__ out)
{
  __shared__ float lpre[2*224*48];     // 86016 B
  __shared__ float ybuf[2*224*28];     // 50176 B
  __shared__ float c1s[16*57];         // 3648 B
  __shared__ float wtscr[3*576];       // 6912 B
  __shared__ int prog[8];
  int tid  = threadIdx.x;
  int blk  = blockIdx.x;
  int r    = blk >> 6;
  int br   = r >> 1, dir = r & 1;
  int b0   = (blk & 63)*2;

  if (tid < 8) ((volatile int*)prog)[tid] = 0;
  __syncthreads();

  if (tid >= 64){
    if (tid < 128){
      // ---------------- y-producer (conv1 -> pool -> conv2) --------------
      int p    = tid - 64;          // 0..63
      int rowq = p >> 2;            // bb*8 + ti
      int q    = p & 3;
      int bb   = rowq >> 3;
      int ti   = rowq & 7;
      int cjs  = q*14;
      const float* w1 = br ? c2w1 : c1w1;
      const float* w2 = br ? c2w2 : c1w2;
      float b1  = br ? c2b1[0] : c1b1[0];
      float b2v = br ? c2b2[0] : c1b2[0];
      float w1r[8];
      #pragma unroll
      for (int kk=0;kk<8;kk++) w1r[kk]=w1[kk];
      float w2r[3];
      #pragma unroll
      for (int kk=0;kk<3;kk++) w2r[kk]=w2[kk];
      const float* xb = x + ((size_t)(br*128 + b0 + bb))*50176;
      volatile int* pv = prog;
      int a0 = 4*cjs - 4;

      for (int g=0; g<28; ++g){
        int step = g*8 + ti;
        int t = dir ? 223-step : step;
        const float* xrow = xb + (size_t)t*224;
        float xr[64];
        #pragma unroll
        for (int qq=0; qq<16; qq++){
          int idx = a0 + 4*qq;
          if (idx >= 0 && idx <= 220){
            float4 v = *(const float4*)(xrow + idx);
            xr[4*qq]=v.x; xr[4*qq+1]=v.y; xr[4*qq+2]=v.z; xr[4*qq+3]=v.w;
          } else {
            #pragma unroll
            for (int e=0;e<4;e++){
              int ii = idx+e;
              xr[4*qq+e] = (ii>=0 && ii<224) ? xrow[ii] : 0.f;
            }
          }
        }
        #pragma unroll
        for (int e=0;e<14;e++){
          float s = b1;
          #pragma unroll
          for (int kk=0;kk<8;kk++) s += xr[4*e+2+kk]*w1r[kk];
          c1s[rowq*57 + cjs + e] = fmaxf(s, 0.f);
        }
        asm volatile("s_waitcnt lgkmcnt(0)" ::: "memory");
        const float* cr = &c1s[rowq*57];
        #pragma unroll
        for (int jj=0;jj<7;jj++){
          int j = q*7 + jj;
          float o = b2v;
          #pragma unroll
          for (int pi=0;pi<3;pi++){
            int pp = j - 1 + pi;
            float pool = 0.f;
            if (pp>=0 && pp<28){
              int i0 = 2*pp - 1;
              float m = -1e30f;
              #pragma unroll
              for (int q2=0;q2<4;q2++){
                int ii = i0+q2;
                if (ii>=0 && ii<56) m = fmaxf(m, cr[ii]);
              }
              pool = fmaxf(m, 0.f);
            }
            o += pool * w2r[pi];
          }
          ybuf[(bb*224 + t)*28 + j] = fmaxf(o, 0.f);
        }
        asm volatile("s_waitcnt lgkmcnt(0)" ::: "memory");
        if (p == 0) pv[0] = g+1;
      }
    } else {
      // ---------------- gate-producers (pregate from ybuf) ---------------
      int p2 = tid - 128;           // 0..127
      if (p2 < 96){
        int fidx = (tid >> 6) - 1;  // 1 for wave2, 2 for wave3
        int bb   = p2 / 48;
        int gate = p2 % 48;
        const float* wih2 = (br ? wihB : wihA) + (dir*48 + gate)*28;
        float4 wq[7];
        #pragma unroll
        for (int q=0;q<7;q++) wq[q] = ((const float4*)wih2)[q];
        float bias = (br ? biasB : biasA)[dir*48 + gate];
        int unit = gate % 12, gg = gate / 12;
        float* lrow = lpre + bb*(224*48) + unit*4 + gg;
        volatile int* pv = prog;

        for (int g=0; g<28; ++g){
          while (pv[0] < g+1) __builtin_amdgcn_s_sleep(2);
          asm volatile("" ::: "memory");
          #pragma unroll
          for (int si=0; si<8; si++){
            int t = dir ? 223-(g*8+si) : (g*8+si);
            const float4* yr = (const float4*)&ybuf[(bb*224 + t)*28];
            float a = bias;
            #pragma unroll
            for (int q=0;q<7;q++){
              float4 yq = yr[q];
              a += yq.x*wq[q].x + yq.y*wq[q].y + yq.z*wq[q].z + yq.w*wq[q].w;
            }
            lrow[t*48] = a;
          }
          asm volatile("s_waitcnt lgkmcnt(0)" ::: "memory");
          if ((p2 & 63) == 0) pv[fidx] = g+1;
        }
      }
    }

    // ---------- post-production: wpartA slices + BCpart (waves 1-3) ------
    {
      int wv   = (tid >> 6) - 1;    // 0..2
      int lane = tid & 63;
      float* wt = wtscr + wv*576;
      for (int tk = blk*3 + wv; tk < 1344; tk += 768){
        int s = tk / 84, j64 = tk % 84;
        #pragma unroll
        for (int q=0;q<9;q++) wt[q*64+lane] = Wtb[q*1024 + s*64 + lane];
        asm volatile("s_waitcnt lgkmcnt(0) vmcnt(0)" ::: "memory");
        int j = j64*64 + lane;
        int nbase = s*64;
        float acc[9];
        #pragma unroll
        for (int o=0;o<9;o++) acc[o]=0.f;
        #pragma unroll 4
        for (int n4=0;n4<16;n4++){
          int nb = nbase + n4*4;
          float4 v4;
          v4.x = fcw1[(size_t)(nb  )*5376 + j];
          v4.y = fcw1[(size_t)(nb+1)*5376 + j];
          v4.z = fcw1[(size_t)(nb+2)*5376 + j];
          v4.w = fcw1[(size_t)(nb+3)*5376 + j];
          #pragma unroll
          for (int o=0;o<9;o++){
            float4 w4 = *(const float4*)&wt[o*64 + n4*4];
            acc[o] += v4.x*w4.x + v4.y*w4.y + v4.z*w4.z + v4.w*w4.w;
          }
        }
        #pragma unroll
        for (int o=0;o<9;o++) wpart[((size_t)s*9+o)*5376 + j] = acc[o];
        if (j64 == 0 && lane < 9){
          float bcp = 0.f;
          for (int n=0;n<64;n++) bcp += wt[lane*64+n]*fcb1[nbase+n];
          BCpart[s*9+lane] = bcp;
        }
        asm volatile("s_waitcnt lgkmcnt(0)" ::: "memory");
      }
    }
    return;
  }

  // ---------------- consumer (lstm chain) ----------------
  int lane = tid;
  int u    = lane & 15;
  int bh   = (lane >> 4) & 1;
  int rbit = lane >> 5;
  int keff = (u < 12) ? u : 11;
  int b    = b0 + bh;
  const float* whh = (br ? whhB : whhA) + dir*48*12;
  LSTM_PREP(whh)
  LSTM_CONSUME3(lpre, out)
}

// ---- K2: layer-2 FUSED: wave0 consumer; waves1-3 pregate producers, then -
// wpartB (Wc reduce) + BC finalize in the consumer's shadow.
__global__ __launch_bounds__(256) __attribute__((amdgpu_waves_per_eu(1,1)))
void lstm2_fused_kernel(const float* __restrict__ ol0,
    const float* __restrict__ whhA, const float* __restrict__ whhB,
    const float* __restrict__ wihA, const float* __restrict__ biasA,
    const float* __restrict__ wihB, const float* __restrict__ biasB,
    const float* __restrict__ wpart, float* __restrict__ Wc,
    const float* __restrict__ fcw3, const float* __restrict__ fcb2,
    const float* __restrict__ fcb3, const float* __restrict__ BCpart,
    float* __restrict__ BC,
    float* __restrict__ out)
{
  __shared__ float lpre[2*224*48];     // 86016 B
  __shared__ int prog[8];
  int tid  = threadIdx.x;
  int blk  = blockIdx.x;
  int r    = blk >> 6;
  int br   = r >> 1, dir = r & 1;
  int b0   = (blk & 63)*2;

  if (tid < 8) ((volatile int*)prog)[tid] = 0;
  __syncthreads();

  if (tid >= 64){
    int p    = tid - 64;          // 0..191
    int wv   = p >> 6;            // 0..2
    int e    = p % 96;
    int th   = p / 96;
    int bb   = e / 48;
    int gate = e % 48;
    const float* wih2 = (br ? wihB : wihA) + (dir*48 + gate)*24;
    float4 wq[6];
    #pragma unroll
    for (int q=0;q<6;q++) wq[q] = ((const float4*)wih2)[q];
    float bias = (br ? biasB : biasA)[dir*48 + gate];
    int unit = gate % 12, gg = gate / 12;
    const float* olrow = ol0 + (size_t)br*(BB*TT*24) + (size_t)(b0+bb)*TT*24;
    float* lrow = lpre + bb*(224*48) + unit*4 + gg;
    volatile int* pv = prog;

    for (int g=0; g<28; g++){
      #pragma unroll
      for (int si=0; si<4; si++){
        int step = g*8 + th*4 + si;
        int t = dir ? 223 - step : step;
        const float4* xr = (const float4*)(olrow + t*24);
        float a = bias;
        #pragma unroll
        for (int q=0;q<6;q++){
          float4 xq = xr[q];
          a += xq.x*wq[q].x + xq.y*wq[q].y + xq.z*wq[q].z + xq.w*wq[q].w;
        }
        lrow[t*48] = a;
      }
      asm volatile("s_waitcnt lgkmcnt(0) vmcnt(0)" ::: "memory");
      if ((p & 63) == 0) pv[wv] = g+1;
    }

    // ---------- post-production: wpartB + BC (consumer's shadow) ---------
    {
      int lane = p & 63;
      int tk = blk*3 + wv;        // 0..767
      if (tk < 756){
        int idx = tk*64 + lane;   // < 48384
        float a = 0.f;
        #pragma unroll
        for (int s=0;s<16;s++) a += wpart[(size_t)s*48384 + idx];
        Wc[idx] = a;
      }
      if (blk == 255 && wv == 2 && lane < 9){
        float acc = fcb3[lane];
        const float* f3 = fcw3 + lane*192;
        for (int pp=0;pp<192;pp++) acc += f3[pp]*fcb2[pp];
        #pragma unroll
        for (int s=0;s<16;s++) acc += BCpart[s*9+lane];
        BC[lane] = acc;
      }
    }
    return;
  }

  int lane = tid;
  int u    = lane & 15;
  int bh   = (lane >> 4) & 1;
  int rbit = lane >> 5;
  int keff = (u < 12) ? u : 11;
  int b    = b0 + bh;
  const float* whh = (br ? whhB : whhA) + dir*48*12;
  LSTM_PREP(whh)
  LSTM_CONSUME3(lpre, out)
}

// ---------------- K6c: out[m][o] = (w1*o1+w2*o2) . Wc[o] + BC[o] ----------
__global__ void final_kernel(const float* __restrict__ o1, const float* __restrict__ o2,
    const float* __restrict__ Wc, const float* __restrict__ BC,
    const float* __restrict__ w1p, const float* __restrict__ w2p,
    float* __restrict__ out)
{
  int wid  = blockIdx.x*4 + (threadIdx.x>>6);
  int lane = threadIdx.x & 63;
  if (wid >= 128*9) return;
  int m = wid / 9, o = wid - m*9;
  float w1 = w1p[0], w2 = w2p[0];
  const float* r1 = o1 + (size_t)m*5376;
  const float* r2 = o2 + (size_t)m*5376;
  const float* wc = Wc + (size_t)o*5376;
  float acc = 0.f;
  for (int i=lane;i<5376;i+=64){
    acc += (w1*r1[i] + w2*r2[i]) * wc[i];
  }
  #pragma unroll
  for (int off=32;off;off>>=1) acc += __shfl_down(acc, off);
  if (lane==0) out[m*9+o] = acc + BC[o];
}

extern "C" void kernel_launch(void* const* d_in, const int* in_sizes, int n_in,
                              void* d_out, int out_size, void* d_ws, size_t ws_size,
                              hipStream_t stream) {
  (void)in_sizes; (void)n_in; (void)out_size; (void)ws_size;
  const float* x    = (const float*)d_in[0];
  const float* c1w1 = (const float*)d_in[1];
  const float* c1b1 = (const float*)d_in[2];
  const float* c1w2 = (const float*)d_in[3];
  const float* c1b2 = (const float*)d_in[4];
  const float* c2w1 = (const float*)d_in[5];
  const float* c2b1 = (const float*)d_in[6];
  const float* c2w2 = (const float*)d_in[7];
  const float* c2b2 = (const float*)d_in[8];
  const float* l10Wih = (const float*)d_in[9];
  const float* l10Whh = (const float*)d_in[10];
  const float* l10b   = (const float*)d_in[11];
  const float* l11Wih = (const float*)d_in[12];
  const float* l11Whh = (const float*)d_in[13];
  const float* l11b   = (const float*)d_in[14];
  const float* l20Wih = (const float*)d_in[15];
  const float* l20Whh = (const float*)d_in[16];
  const float* l20b   = (const float*)d_in[17];
  const float* l21Wih = (const float*)d_in[18];
  const float* l21Whh = (const float*)d_in[19];
  const float* l21b   = (const float*)d_in[20];
  const float* fcw1 = (const float*)d_in[21];
  const float* fcb1 = (const float*)d_in[22];
  const float* fcw2 = (const float*)d_in[23];
  const float* fcb2 = (const float*)d_in[24];
  const float* fcw3 = (const float*)d_in[25];
  const float* fcb3 = (const float*)d_in[26];
  const float* w1   = (const float*)d_in[27];
  const float* w2   = (const float*)d_in[28];
  float* out = (float*)d_out;

  float* ws  = (float*)d_ws;
  float* wpart = ws;                      // 774144
  float* ol0  = ws + 2*802816 + 4*1376256;
  float* ol1  = ol0 + 2*688128;
  float* Wc   = ol1 + 2*688128;
  float* BC   = Wc  + 48384;
  float* BCpart = BC + 9;
  float* Wtb  = BCpart + 144;             // 9216

  wtb_kernel<<<36,256,0,stream>>>(fcw2, fcw3, Wtb);
  lstm1_fused_kernel<<<256,256,0,stream>>>(x, l10Whh, l20Whh,
      l10Wih, l10b, l20Wih, l20b,
      c1w1,c1b1,c1w2,c1b2, c2w1,c2b1,c2w2,c2b2,
      fcw1, fcb1, Wtb, wpart, BCpart, ol0);
  lstm2_fused_kernel<<<256,256,0,stream>>>(ol0, l11Whh, l21Whh,
      l11Wih, l11b, l21Wih, l21b,
      wpart, Wc, fcw3, fcb2, fcb3, BCpart, BC, ol1);
  final_kernel<<<288,256,0,stream>>>(ol1, ol1+688128, Wc, BC, w1, w2, out);
}